// Round 3
// baseline (375.569 us; speedup 1.0000x reference)
//
#include <hip/hip_runtime.h>
#include <math.h>

// Problem constants (from reference)
#define NN 50000
#define EE 800000
#define NBK 196    // node buckets (256 nodes each): ceil(50000/256)
#define EPB 4096   // edges per pass-A block: ceil(800000/4096) = 196 blocks

typedef short v8s __attribute__((ext_vector_type(8)));
typedef float v4f __attribute__((ext_vector_type(4)));

__device__ __forceinline__ ushort f2bf(float f) {
    uint u = __float_as_uint(f);
    uint r = (u + 0x7fffu + ((u >> 16) & 1u)) >> 16;
    return (ushort)r;
}
__device__ __forceinline__ float bf2f(ushort h) {
    return __uint_as_float(((uint)h) << 16);
}
// leaky_relu(x,0.2) = 0.6x + 0.4|x|
__device__ __forceinline__ float lrelu(float x) {
    return fmaf(0.4f, fabsf(x), 0.6f * x);
}

// DPP partial reductions (no LDS pipe).
template <int CTRL>
__device__ __forceinline__ float dppadd(float x) {
    int y = __builtin_amdgcn_update_dpp(0, __float_as_int(x), CTRL, 0xf, 0xf, true);
    return x + __int_as_float(y);
}
__device__ __forceinline__ float sum8(float x) {   // all-lane sum within 8-groups
    x = dppadd<0xB1>(x);    // quad_perm xor1
    x = dppadd<0x4E>(x);    // quad_perm xor2
    x = dppadd<0x141>(x);   // row_half_mirror
    return x;
}
__device__ __forceinline__ float sum16(float x) {  // all-lane sum within 16-rows
    x = sum8(x);
    x = dppadd<0x140>(x);   // row_mirror
    return x;
}
__device__ __forceinline__ float expclamp(float t) {
    return __expf(fminf(fmaxf(t, -60.f), 80.f));
}

// ---------------------------------------------------------------------------
// Bucketed CSR build — no per-node global atomics, no random global writes.
// ---------------------------------------------------------------------------
__global__ __launch_bounds__(256) void k_bktcnt(const int* __restrict__ edst,
                                                int* __restrict__ bcnt) {
    __shared__ int h[NBK];
    int t = threadIdx.x;
    if (t < NBK) h[t] = 0;
    __syncthreads();
    int eb = blockIdx.x * EPB;
    #pragma unroll
    for (int k = 0; k < EPB / 256; ++k) {
        int e = eb + k * 256 + t;
        if (e < EE) atomicAdd(&h[edst[e] >> 8], 1);
    }
    __syncthreads();
    if (t < NBK && h[t]) atomicAdd(&bcnt[t], h[t]);
}

__global__ __launch_bounds__(256) void k_bscan(const int* __restrict__ bcnt,
                                               int* __restrict__ bbase,
                                               int* __restrict__ bcur) {
    __shared__ int sm[256];
    int t = threadIdx.x;
    int v = (t < NBK) ? bcnt[t] : 0;
    sm[t] = v;
    __syncthreads();
    for (int o = 1; o < 256; o <<= 1) {
        int a = (t >= o) ? sm[t - o] : 0;
        __syncthreads();
        sm[t] += a;
        __syncthreads();
    }
    if (t < NBK) { int ex = sm[t] - v; bbase[t] = ex; bcur[t] = ex; }
}

__global__ __launch_bounds__(256) void k_bktplace(const int* __restrict__ esrc,
                                                  const int* __restrict__ edst,
                                                  int* __restrict__ bcur,
                                                  uint* __restrict__ ebuf) {
    __shared__ int h[NBK];
    __shared__ int base[NBK];
    int t = threadIdx.x;
    if (t < NBK) h[t] = 0;
    __syncthreads();
    int eb = blockIdx.x * EPB;
    int pk[EPB / 256];   // (bucket<<16)|local_rank per edge
    #pragma unroll
    for (int k = 0; k < EPB / 256; ++k) {
        int e = eb + k * 256 + t;
        pk[k] = -1;
        if (e < EE) {
            int b = edst[e] >> 8;
            int r = atomicAdd(&h[b], 1);
            pk[k] = (b << 16) | r;
        }
    }
    __syncthreads();
    if (t < NBK && h[t]) base[t] = atomicAdd(&bcur[t], h[t]);
    __syncthreads();
    #pragma unroll
    for (int k = 0; k < EPB / 256; ++k) {
        int e = eb + k * 256 + t;
        if (e < EE) {
            int b = pk[k] >> 16;
            int r = pk[k] & 0xFFFF;
            uint dl = (uint)(edst[e] & 255);
            ebuf[base[b] + r] = (dl << 16) | (uint)esrc[e];
        }
    }
}

// one block per bucket: per-node degree + scan + cursor all in LDS.
__global__ __launch_bounds__(256) void k_bktfin(const uint* __restrict__ ebuf,
                                                const int* __restrict__ bbase,
                                                const int* __restrict__ bcnt,
                                                int* __restrict__ rowptr,
                                                int* __restrict__ csrc) {
    __shared__ int deg[256];
    __shared__ int sm[256];
    __shared__ int cur[256];
    const int b = blockIdx.x;
    const int t = threadIdx.x;
    const int eb = bbase[b];
    const int ec = bcnt[b];
    deg[t] = 0;
    __syncthreads();
    for (int k = t; k < ec; k += 256)
        atomicAdd(&deg[ebuf[eb + k] >> 16], 1);
    __syncthreads();
    int v = deg[t];
    sm[t] = v;
    __syncthreads();
    for (int o = 1; o < 256; o <<= 1) {
        int a = (t >= o) ? sm[t - o] : 0;
        __syncthreads();
        sm[t] += a;
        __syncthreads();
    }
    int node = b * 256 + t;
    if (node < NN) rowptr[node + 1] = eb + sm[t];
    if (node == 0) rowptr[0] = 0;
    cur[t] = sm[t] - v;   // exclusive
    __syncthreads();
    for (int k = t; k < ec; k += 256) {
        uint u = ebuf[eb + k];
        int nl = (int)(u >> 16);
        int r = atomicAdd(&cur[nl], 1);
        csrc[eb + r] = (int)(u & 0xFFFFu);
    }
}

// ---------------------------------------------------------------------------
// Weight conversion: W [128 x FOUT] fp32 -> bf16 hi/lo in MFMA-fragment order.
// ---------------------------------------------------------------------------
struct WPack {
    const float* W[8];
    ushort* Th[8];
    ushort* Tl[8];
    int fout[8];
};

__global__ __launch_bounds__(256) void k_conv_w(WPack p) {
    int wi = blockIdx.y;
    int fout = p.fout[wi];
    int total = 128 * fout;
    int i = blockIdx.x * 256 + threadIdx.x;
    if (i >= total) return;
    int k = i / fout;
    int n = i - k * fout;
    float f = p.W[wi][i];
    ushort h = f2bf(f);
    float lo = f - bf2f(h);
    int t = n >> 4, m = n & 15, c = k >> 5, quad = (k >> 3) & 3, j = k & 7;
    int flat = ((((t * 4 + c) * 4 + quad) * 16 + m) << 3) + j;
    p.Th[wi][flat] = h;
    p.Tl[wi][flat] = f2bf(lo);
}

// ---------------------------------------------------------------------------
// Fused split-bf16 MFMA GEMM + attention-dot epilogue, t-SPLIT for occupancy:
// blockIdx.y selects a TS-wide slice of the 16-col t-steps. FOUT=128: TS=2,
// grid.y=4 -> each block covers exactly one head; dot flushed directly.
// FOUT=64 (1 head spans 4 t): TS=2, grid.y=2; dot partials via atomicAdd
// into pre-zeroed DL/DR.
//   dotL[n,h] = 0.6 * att[h]·(xl[n]+bl)  -> DL[n*NH+h]
//   dotR[n,h] = 0.6 * att[h]·(xr[n]+br)  -> DR[n*NH+h]
// ---------------------------------------------------------------------------
template <int FOUT, int NMAT, bool CVT, int TS>
__global__ __launch_bounds__(256) void k_gemm_fused(
    const float* __restrict__ Xf,
    const ushort* __restrict__ Xh, const ushort* __restrict__ Xl,
    const ushort* __restrict__ T0h, const ushort* __restrict__ T0l, const float* __restrict__ B0,
    const ushort* __restrict__ T1h, const ushort* __restrict__ T1l, const float* __restrict__ B1,
    const ushort* __restrict__ T2h, const ushort* __restrict__ T2l,
    const float* __restrict__ ATT, float* __restrict__ DL, float* __restrict__ DR,
    ushort* __restrict__ O0b, float* __restrict__ O1, float* __restrict__ O2)
{
    const int lane = threadIdx.x & 63;
    const int wid  = threadIdx.x >> 6;
    const int m    = lane & 15;
    const int quad = lane >> 4;
    const int row0 = blockIdx.x * 64 + wid * 16;
    const int t0   = blockIdx.y * TS;

    v8s ah[4], al[4];
    {
        int arow = row0 + m;
        if (arow > NN - 1) arow = NN - 1;
        #pragma unroll
        for (int c = 0; c < 4; ++c) {
            size_t off = (size_t)arow * 128 + c * 32 + quad * 8;
            if constexpr (CVT) {
                float4 f0 = *(const float4*)(Xf + off);
                float4 f1 = *(const float4*)(Xf + off + 4);
                const float fe[8] = {f0.x, f0.y, f0.z, f0.w, f1.x, f1.y, f1.z, f1.w};
                #pragma unroll
                for (int e = 0; e < 8; ++e) {
                    ushort h = f2bf(fe[e]);
                    float lo = fe[e] - bf2f(h);
                    ah[c][e] = (short)h;
                    al[c][e] = (short)(__float_as_uint(lo) >> 16);  // truncate lo
                }
            } else {
                ah[c] = *(const v8s*)(Xh + off);
                al[c] = *(const v8s*)(Xl + off);
            }
        }
    }

    float dp0[4] = {0.f, 0.f, 0.f, 0.f};
    float dp1[4] = {0.f, 0.f, 0.f, 0.f};

    #pragma unroll
    for (int tt = 0; tt < TS; ++tt) {
        const int t = t0 + tt;
        v4f a0 = {0.f, 0.f, 0.f, 0.f};
        v4f a1 = {0.f, 0.f, 0.f, 0.f};
        v4f a2 = {0.f, 0.f, 0.f, 0.f};
        #pragma unroll
        for (int c = 0; c < 4; ++c) {
            const int boff = t * 2048 + (c * 4 + quad) * 128 + m * 8;
            v8s b0h = *(const v8s*)(T0h + boff);
            v8s b0l = *(const v8s*)(T0l + boff);
            v8s b1h = *(const v8s*)(T1h + boff);
            v8s b1l = *(const v8s*)(T1l + boff);
            a0 = __builtin_amdgcn_mfma_f32_16x16x32_bf16(al[c], b0h, a0, 0, 0, 0);
            a1 = __builtin_amdgcn_mfma_f32_16x16x32_bf16(al[c], b1h, a1, 0, 0, 0);
            a0 = __builtin_amdgcn_mfma_f32_16x16x32_bf16(ah[c], b0l, a0, 0, 0, 0);
            a1 = __builtin_amdgcn_mfma_f32_16x16x32_bf16(ah[c], b1l, a1, 0, 0, 0);
            a0 = __builtin_amdgcn_mfma_f32_16x16x32_bf16(ah[c], b0h, a0, 0, 0, 0);
            a1 = __builtin_amdgcn_mfma_f32_16x16x32_bf16(ah[c], b1h, a1, 0, 0, 0);
            if constexpr (NMAT == 3) {
                v8s b2h = *(const v8s*)(T2h + boff);
                v8s b2l = *(const v8s*)(T2l + boff);
                a2 = __builtin_amdgcn_mfma_f32_16x16x32_bf16(al[c], b2h, a2, 0, 0, 0);
                a2 = __builtin_amdgcn_mfma_f32_16x16x32_bf16(ah[c], b2l, a2, 0, 0, 0);
                a2 = __builtin_amdgcn_mfma_f32_16x16x32_bf16(ah[c], b2h, a2, 0, 0, 0);
            }
        }
        const int col = t * 16 + m;
        const float bad0 = B0[col];
        const float bad1 = B1[col];
        const float attc = ATT[col];
        #pragma unroll
        for (int j = 0; j < 4; ++j) {
            float o0v = a0[j] + bad0;
            float o1v = a1[j] + bad1;
            dp0[j] = fmaf(attc, o0v, dp0[j]);
            dp1[j] = fmaf(attc, o1v, dp1[j]);
            int r = row0 + quad * 4 + j;
            if (r < NN) {
                O0b[(size_t)r * FOUT + col] = f2bf(o0v);
                O1[(size_t)r * FOUT + col] = o1v;
                if constexpr (NMAT == 3) O2[(size_t)r * FOUT + col] = a2[j];
            }
        }
        if constexpr (FOUT == 128) {
            if ((t & 1) == 1) {   // head h = t>>1 complete -> reduce + store
                const int h = t >> 1;
                #pragma unroll
                for (int j = 0; j < 4; ++j) {
                    float s0 = sum16(dp0[j]);
                    float s1 = sum16(dp1[j]);
                    int r = row0 + quad * 4 + j;
                    if (m == 0 && r < NN) {
                        DL[(size_t)r * 4 + h] = 0.6f * s0;
                        DR[(size_t)r * 4 + h] = 0.6f * s1;
                    }
                    dp0[j] = 0.f;
                    dp1[j] = 0.f;
                }
            }
        }
    }
    if constexpr (FOUT == 64) {   // head spans all 4 t -> partial, atomic
        #pragma unroll
        for (int j = 0; j < 4; ++j) {
            float s0 = sum16(dp0[j]);
            float s1 = sum16(dp1[j]);
            int r = row0 + quad * 4 + j;
            if (m == 0 && r < NN) {
                atomicAdd(&DL[r], 0.6f * s0);
                atomicAdd(&DR[r], 0.6f * s1);
            }
        }
    }
}

// ---------------------------------------------------------------------------
// Aggregation layers 0/1: one wave per node, 8-edge main loop (4 gathers in
// flight) + masked 2-edge tail. logit decomposed:
//   logit = dotL[src,h] + dotR[dst,h] + sum_c (0.4*att_c)*|xl_c + xr_c|
// DL is a separate L2-hot table [NN*4].
// ---------------------------------------------------------------------------
__global__ __launch_bounds__(256) void k_agg01(const ushort* __restrict__ XLb,
                                               const float4* __restrict__ XR4,
                                               const float4* __restrict__ RES4,
                                               const float* __restrict__ att,
                                               const float* __restrict__ bias,
                                               const float* __restrict__ DL,
                                               const float* __restrict__ DR,
                                               const int* __restrict__ rowptr,
                                               const int* __restrict__ csrc,
                                               ushort* __restrict__ Hh,
                                               ushort* __restrict__ Hl) {
    const int lane = threadIdx.x & 63;
    const int wid = threadIdx.x >> 6;
    const int n = blockIdx.x * 4 + wid;
    if (n >= NN) return;
    const int beg = rowptr[n];
    const int end = rowptr[n + 1];
    const int half = lane >> 5;
    const uint j = lane & 31;
    const uint head = j >> 3;

    const float4 xr = XR4[(uint)n * 32u + j];
    float4 at = ((const float4*)att)[j];
    at.x *= 0.4f; at.y *= 0.4f; at.z *= 0.4f; at.w *= 0.4f;
    const float dRn = DR[(uint)n * 4u + head];
    float4 s = {0.f, 0.f, 0.f, 0.f};
    float d = 0.f;

#define EDGE01(U, DLV)  {                                             \
    float4 v = {bf2f((U).x), bf2f((U).y), bf2f((U).z), bf2f((U).w)};  \
    float t0 =      at.x * fabsf(v.x + xr.x);                         \
    t0 = fmaf(at.y, fabsf(v.y + xr.y), t0);                           \
    t0 = fmaf(at.z, fabsf(v.z + xr.z), t0);                           \
    t0 = fmaf(at.w, fabsf(v.w + xr.w), t0);                           \
    float p = expclamp(sum8(t0) + (DLV) + dRn);                       \
    d += p;                                                            \
    s.x = fmaf(p, v.x, s.x); s.y = fmaf(p, v.y, s.y);                 \
    s.z = fmaf(p, v.z, s.z); s.w = fmaf(p, v.w, s.w); }

    int i = beg;
    for (; i + 8 <= end; i += 8) {
        uint sa = (uint)csrc[i + half];
        uint sb = (uint)csrc[i + 2 + half];
        uint sc = (uint)csrc[i + 4 + half];
        uint sd = (uint)csrc[i + 6 + half];
        ushort4 ua = *(const ushort4*)(XLb + (size_t)sa * 128u + 4u * j);
        float  da_ = DL[(size_t)sa * 4u + head];
        ushort4 ub = *(const ushort4*)(XLb + (size_t)sb * 128u + 4u * j);
        float  db_ = DL[(size_t)sb * 4u + head];
        ushort4 uc = *(const ushort4*)(XLb + (size_t)sc * 128u + 4u * j);
        float  dc_ = DL[(size_t)sc * 4u + head];
        ushort4 ud = *(const ushort4*)(XLb + (size_t)sd * 128u + 4u * j);
        float  dd_ = DL[(size_t)sd * 4u + head];
        EDGE01(ua, da_)
        EDGE01(ub, db_)
        EDGE01(uc, dc_)
        EDGE01(ud, dd_)
    }
    for (; i < end; i += 2) {
        int ia = i + half;
        if (ia > end - 1) ia = end - 1;
        uint sa = (uint)csrc[ia];
        ushort4 ua = *(const ushort4*)(XLb + (size_t)sa * 128u + 4u * j);
        float  da_ = DL[(size_t)sa * 4u + head];
        float4 v = {bf2f(ua.x), bf2f(ua.y), bf2f(ua.z), bf2f(ua.w)};
        float t0 =      at.x * fabsf(v.x + xr.x);
        t0 = fmaf(at.y, fabsf(v.y + xr.y), t0);
        t0 = fmaf(at.z, fabsf(v.z + xr.z), t0);
        t0 = fmaf(at.w, fabsf(v.w + xr.w), t0);
        float p = expclamp(sum8(t0) + da_ + dRn);
        if (half && (i + 1 >= end)) p = 0.f;
        d += p;
        s.x = fmaf(p, v.x, s.x); s.y = fmaf(p, v.y, s.y);
        s.z = fmaf(p, v.z, s.z); s.w = fmaf(p, v.w, s.w);
    }
#undef EDGE01

    d   += __shfl_xor(d, 32);
    s.x += __shfl_xor(s.x, 32);
    s.y += __shfl_xor(s.y, 32);
    s.z += __shfl_xor(s.z, 32);
    s.w += __shfl_xor(s.w, 32);

    if (half == 0) {
        float inv = (d > 0.f) ? 1.f / d : 0.f;
        float4 rv = RES4[(uint)n * 32u + j];
        float4 bv = ((const float4*)bias)[j];
        float o0 = fmaf(s.x, inv, rv.x + bv.x);
        float o1 = fmaf(s.y, inv, rv.y + bv.y);
        float o2 = fmaf(s.z, inv, rv.z + bv.z);
        float o3 = fmaf(s.w, inv, rv.w + bv.w);
        o0 = o0 > 0.f ? o0 : __expf(o0) - 1.f;   // ELU
        o1 = o1 > 0.f ? o1 : __expf(o1) - 1.f;
        o2 = o2 > 0.f ? o2 : __expf(o2) - 1.f;
        o3 = o3 > 0.f ? o3 : __expf(o3) - 1.f;
        ushort4 h, l;
        h.x = f2bf(o0); l.x = f2bf(o0 - bf2f(h.x));
        h.y = f2bf(o1); l.y = f2bf(o1 - bf2f(h.y));
        h.z = f2bf(o2); l.z = f2bf(o2 - bf2f(h.z));
        h.w = f2bf(o3); l.w = f2bf(o3 - bf2f(h.w));
        *(ushort4*)(Hh + (uint)n * 128u + 4u * j) = h;
        *(ushort4*)(Hl + (uint)n * 128u + 4u * j) = l;
    }
}

// ---------------------------------------------------------------------------
// Aggregation layer 2: F=64, H=1. 8 edges per iteration (2 masked
// quad-passes). sum16 over channel lanes. DL/DR are [NN] fp32.
// ---------------------------------------------------------------------------
__global__ __launch_bounds__(256) void k_agg2(const ushort* __restrict__ XLb,
                                              const float4* __restrict__ XR4,
                                              const float* __restrict__ att,
                                              const float* __restrict__ bias,
                                              const float* __restrict__ DL,
                                              const float* __restrict__ DR,
                                              const int* __restrict__ rowptr,
                                              const int* __restrict__ csrc,
                                              float* __restrict__ OUT) {
    const int lane = threadIdx.x & 63;
    const int wid = threadIdx.x >> 6;
    const int n = blockIdx.x * 4 + wid;
    if (n >= NN) return;
    const int beg = rowptr[n];
    const int end = rowptr[n + 1];
    const int q = lane >> 4;
    const uint jj = lane & 15;

    const float4 xr = XR4[(uint)n * 16u + jj];
    float4 at = ((const float4*)att)[jj];
    at.x *= 0.4f; at.y *= 0.4f; at.z *= 0.4f; at.w *= 0.4f;
    const float dRn = DR[n];
    float4 s = {0.f, 0.f, 0.f, 0.f};
    float d = 0.f;
    const int e1 = end - 1;

    for (int i = beg; i < end; i += 8) {
        int i0 = i + q;
        int i1 = i + 4 + q;
        uint s0 = (uint)csrc[min(i0, e1)];
        uint s1 = (uint)csrc[min(i1, e1)];
        ushort4 u0 = *(const ushort4*)(XLb + (size_t)s0 * 64u + 4u * jj);
        float  dl0 = DL[s0];
        ushort4 u1 = *(const ushort4*)(XLb + (size_t)s1 * 64u + 4u * jj);
        float  dl1 = DL[s1];
        #pragma unroll
        for (int u = 0; u < 2; ++u) {
            ushort4 uv = (u == 0) ? u0 : u1;
            float  dlv = (u == 0) ? dl0 : dl1;
            int ii = (u == 0) ? i0 : i1;
            float4 v = {bf2f(uv.x), bf2f(uv.y), bf2f(uv.z), bf2f(uv.w)};
            float t0 =      at.x * fabsf(v.x + xr.x);
            t0 = fmaf(at.y, fabsf(v.y + xr.y), t0);
            t0 = fmaf(at.z, fabsf(v.z + xr.z), t0);
            t0 = fmaf(at.w, fabsf(v.w + xr.w), t0);
            float p = expclamp(sum16(t0) + dlv + dRn);
            if (ii >= end) p = 0.f;
            d += p;
            s.x = fmaf(p, v.x, s.x); s.y = fmaf(p, v.y, s.y);
            s.z = fmaf(p, v.z, s.z); s.w = fmaf(p, v.w, s.w);
        }
    }

    d   += __shfl_xor(d, 16);   d   += __shfl_xor(d, 32);
    s.x += __shfl_xor(s.x, 16); s.x += __shfl_xor(s.x, 32);
    s.y += __shfl_xor(s.y, 16); s.y += __shfl_xor(s.y, 32);
    s.z += __shfl_xor(s.z, 16); s.z += __shfl_xor(s.z, 32);
    s.w += __shfl_xor(s.w, 16); s.w += __shfl_xor(s.w, 32);

    if (lane < 16) {
        float inv = (d > 0.f) ? 1.f / d : 0.f;
        float4 bv = ((const float4*)bias)[jj];
        float4 o;
        o.x = fmaf(s.x, inv, bv.x);
        o.y = fmaf(s.y, inv, bv.y);
        o.z = fmaf(s.z, inv, bv.z);
        o.w = fmaf(s.w, inv, bv.w);
        *(float4*)(OUT + (uint)n * 64u + 4u * jj) = o;
    }
}

// ---------------------------------------------------------------------------
extern "C" void kernel_launch(void* const* d_in, const int* in_sizes, int n_in,
                              void* d_out, int out_size, void* d_ws, size_t ws_size,
                              hipStream_t stream) {
    const float* x    = (const float*)d_in[0];
    const int*   ei   = (const int*)d_in[1];
    const int*   esrc = ei;
    const int*   edst = ei + EE;

    const float* Wl0 = (const float*)d_in[2];
    const float* bl0 = (const float*)d_in[3];
    const float* Wr0 = (const float*)d_in[4];
    const float* br0 = (const float*)d_in[5];
    const float* at0 = (const float*)d_in[6];
    const float* b0  = (const float*)d_in[7];
    const float* rs0 = (const float*)d_in[8];
    const float* Wl1 = (const float*)d_in[9];
    const float* bl1 = (const float*)d_in[10];
    const float* Wr1 = (const float*)d_in[11];
    const float* br1 = (const float*)d_in[12];
    const float* at1 = (const float*)d_in[13];
    const float* b1  = (const float*)d_in[14];
    const float* rs1 = (const float*)d_in[15];
    const float* Wl2 = (const float*)d_in[16];
    const float* bl2 = (const float*)d_in[17];
    const float* Wr2 = (const float*)d_in[18];
    const float* br2 = (const float*)d_in[19];
    const float* at2 = (const float*)d_in[20];
    const float* b2  = (const float*)d_in[21];

    float* out = (float*)d_out;

    // --- workspace layout ---
    ushort* XLb = (ushort*)d_ws;               // [NN*128] bf16 (gather payload)
    float* XR  = (float*)(XLb + (size_t)NN * 128);    // [NN*128] fp32
    float* RES = XR + (size_t)NN * 128;               // [NN*128] fp32
    ushort* Xh = (ushort*)(RES + (size_t)NN * 128);   // [NN*128] bf16-hi (H)
    ushort* Xl_ = Xh + (size_t)NN * 128;              // [NN*128] bf16-lo (H)
    float* DLarr = (float*)(Xl_ + (size_t)NN * 128);  // [NN*4] fp32 dotL
    float* DRarr = DLarr + (size_t)NN * 4;            // [NN*4] fp32 dotR
    ushort* Wth = (ushort*)(DRarr + (size_t)NN * 4);
    const int wsz[8] = {16384, 16384, 16384, 16384, 16384, 16384, 8192, 8192};
    ushort* th[8]; ushort* tl[8];
    {
        ushort* p = Wth;
        for (int i = 0; i < 8; ++i) { th[i] = p; p += wsz[i]; }
        for (int i = 0; i < 8; ++i) { tl[i] = p; p += wsz[i]; }
    }
    int* bcnt   = (int*)(Wth + 2 * (6 * 16384 + 2 * 8192));  // 256 (memset)
    int* bbase  = bcnt + 256;                  // 256
    int* bcur   = bbase + 256;                 // 256
    int* rowptr = bcur + 256;                  // NN+1
    int* csrc   = rowptr + (NN + 1);           // EE
    uint* ebuf  = (uint*)(csrc + EE);          // EE

    // --- bucketed CSR build (graph identical across layers) ---
    hipMemsetAsync(bcnt, 0, 256 * sizeof(int), stream);
    const int ebk = (EE + EPB - 1) / EPB;      // 196
    k_bktcnt<<<ebk, 256, 0, stream>>>(edst, bcnt);
    k_bscan<<<1, 256, 0, stream>>>(bcnt, bbase, bcur);
    k_bktplace<<<ebk, 256, 0, stream>>>(esrc, edst, bcur, ebuf);
    k_bktfin<<<NBK, 256, 0, stream>>>(ebuf, bbase, bcnt, rowptr, csrc);

    // --- weight conversion ---
    WPack wp;
    const float* Ws[8] = {Wl0, Wr0, rs0, Wl1, Wr1, rs1, Wl2, Wr2};
    const int fouts[8] = {128, 128, 128, 128, 128, 128, 64, 64};
    for (int i = 0; i < 8; ++i) { wp.W[i] = Ws[i]; wp.Th[i] = th[i]; wp.Tl[i] = tl[i]; wp.fout[i] = fouts[i]; }
    k_conv_w<<<dim3(64, 8), 256, 0, stream>>>(wp);

    const int gemm_gx = (NN + 63) / 64;        // 782 row-tiles
    const int agg_grid = (NN + 3) / 4;

    // --- Layer 0 (A from fp32 x; 3 weight mats fused; grid.y = t-slice) ---
    k_gemm_fused<128, 3, true, 2><<<dim3(gemm_gx, 4), 256, 0, stream>>>(x, nullptr, nullptr,
        th[0], tl[0], bl0, th[1], tl[1], br0, th[2], tl[2], at0, DLarr, DRarr, XLb, XR, RES);
    k_agg01<<<agg_grid, 256, 0, stream>>>(XLb, (const float4*)XR, (const float4*)RES,
        at0, b0, DLarr, DRarr, rowptr, csrc, Xh, Xl_);

    // --- Layer 1 ---
    k_gemm_fused<128, 3, false, 2><<<dim3(gemm_gx, 4), 256, 0, stream>>>(nullptr, Xh, Xl_,
        th[3], tl[3], bl1, th[4], tl[4], br1, th[5], tl[5], at1, DLarr, DRarr, XLb, XR, RES);
    k_agg01<<<agg_grid, 256, 0, stream>>>(XLb, (const float4*)XR, (const float4*)RES,
        at1, b1, DLarr, DRarr, rowptr, csrc, Xh, Xl_);

    // --- Layer 2 (heads=1, C=64; dot partials via atomics into zeroed DL/DR) ---
    hipMemsetAsync(DLarr, 0, NN * sizeof(float), stream);
    hipMemsetAsync(DRarr, 0, NN * sizeof(float), stream);
    k_gemm_fused<64, 2, false, 2><<<dim3(gemm_gx, 2), 256, 0, stream>>>(nullptr, Xh, Xl_,
        th[6], tl[6], bl2, th[7], tl[7], br2, nullptr, nullptr, at2, DLarr, DRarr, XLb, XR, nullptr);
    k_agg2<<<agg_grid, 256, 0, stream>>>(XLb, (const float4*)XR, at2, b2, DLarr, DRarr, rowptr, csrc, out);
}

// Round 4
// 359.086 us; speedup vs baseline: 1.0459x; 1.0459x over previous
//
#include <hip/hip_runtime.h>
#include <math.h>

// Problem constants (from reference)
#define NN 50000
#define EE 800000
#define NBK 196    // node buckets (256 nodes each): ceil(50000/256)
#define EPB 4096   // edges per pass-A block: ceil(800000/4096) = 196 blocks

typedef short v8s __attribute__((ext_vector_type(8)));
typedef float v4f __attribute__((ext_vector_type(4)));

__device__ __forceinline__ ushort f2bf(float f) {
    uint u = __float_as_uint(f);
    uint r = (u + 0x7fffu + ((u >> 16) & 1u)) >> 16;
    return (ushort)r;
}
__device__ __forceinline__ float bf2f(ushort h) {
    return __uint_as_float(((uint)h) << 16);
}
// leaky_relu(x,0.2) = 0.6x + 0.4|x|
__device__ __forceinline__ float lrelu(float x) {
    return fmaf(0.4f, fabsf(x), 0.6f * x);
}

// async global->LDS, 16B per lane (dest = wave-uniform base + lane*16)
__device__ __forceinline__ void gld_lds16(const void* g, void* l) {
    __builtin_amdgcn_global_load_lds(
        (const __attribute__((address_space(1))) void*)g,
        (__attribute__((address_space(3))) void*)l, 16, 0, 0);
}

// DPP partial reductions (no LDS pipe).
template <int CTRL>
__device__ __forceinline__ float dppadd(float x) {
    int y = __builtin_amdgcn_update_dpp(0, __float_as_int(x), CTRL, 0xf, 0xf, true);
    return x + __int_as_float(y);
}
__device__ __forceinline__ float sum8(float x) {   // all-lane sum within 8-groups
    x = dppadd<0xB1>(x);    // quad_perm xor1
    x = dppadd<0x4E>(x);    // quad_perm xor2
    x = dppadd<0x141>(x);   // row_half_mirror
    return x;
}
__device__ __forceinline__ float sum16(float x) {  // all-lane sum within 16-rows
    x = sum8(x);
    x = dppadd<0x140>(x);   // row_mirror
    return x;
}
__device__ __forceinline__ float expclamp(float t) {
    return __expf(fminf(fmaxf(t, -60.f), 80.f));
}

// ---------------------------------------------------------------------------
// Bucketed CSR build — no per-node global atomics, no random global writes.
// ---------------------------------------------------------------------------
__global__ __launch_bounds__(256) void k_bktcnt(const int* __restrict__ edst,
                                                int* __restrict__ bcnt) {
    __shared__ int h[NBK];
    int t = threadIdx.x;
    if (t < NBK) h[t] = 0;
    __syncthreads();
    int eb = blockIdx.x * EPB;
    #pragma unroll
    for (int k = 0; k < EPB / 256; ++k) {
        int e = eb + k * 256 + t;
        if (e < EE) atomicAdd(&h[edst[e] >> 8], 1);
    }
    __syncthreads();
    if (t < NBK && h[t]) atomicAdd(&bcnt[t], h[t]);
}

__global__ __launch_bounds__(256) void k_bscan(const int* __restrict__ bcnt,
                                               int* __restrict__ bbase,
                                               int* __restrict__ bcur) {
    __shared__ int sm[256];
    int t = threadIdx.x;
    int v = (t < NBK) ? bcnt[t] : 0;
    sm[t] = v;
    __syncthreads();
    for (int o = 1; o < 256; o <<= 1) {
        int a = (t >= o) ? sm[t - o] : 0;
        __syncthreads();
        sm[t] += a;
        __syncthreads();
    }
    if (t < NBK) { int ex = sm[t] - v; bbase[t] = ex; bcur[t] = ex; }
}

__global__ __launch_bounds__(256) void k_bktplace(const int* __restrict__ esrc,
                                                  const int* __restrict__ edst,
                                                  int* __restrict__ bcur,
                                                  uint* __restrict__ ebuf) {
    __shared__ int h[NBK];
    __shared__ int base[NBK];
    int t = threadIdx.x;
    if (t < NBK) h[t] = 0;
    __syncthreads();
    int eb = blockIdx.x * EPB;
    int pk[EPB / 256];   // (bucket<<16)|local_rank per edge
    #pragma unroll
    for (int k = 0; k < EPB / 256; ++k) {
        int e = eb + k * 256 + t;
        pk[k] = -1;
        if (e < EE) {
            int b = edst[e] >> 8;
            int r = atomicAdd(&h[b], 1);
            pk[k] = (b << 16) | r;
        }
    }
    __syncthreads();
    if (t < NBK && h[t]) base[t] = atomicAdd(&bcur[t], h[t]);
    __syncthreads();
    #pragma unroll
    for (int k = 0; k < EPB / 256; ++k) {
        int e = eb + k * 256 + t;
        if (e < EE) {
            int b = pk[k] >> 16;
            int r = pk[k] & 0xFFFF;
            uint dl = (uint)(edst[e] & 255);
            ebuf[base[b] + r] = (dl << 16) | (uint)esrc[e];
        }
    }
}

// one block per bucket: per-node degree + scan + cursor all in LDS.
__global__ __launch_bounds__(256) void k_bktfin(const uint* __restrict__ ebuf,
                                                const int* __restrict__ bbase,
                                                const int* __restrict__ bcnt,
                                                int* __restrict__ rowptr,
                                                int* __restrict__ csrc) {
    __shared__ int deg[256];
    __shared__ int sm[256];
    __shared__ int cur[256];
    const int b = blockIdx.x;
    const int t = threadIdx.x;
    const int eb = bbase[b];
    const int ec = bcnt[b];
    deg[t] = 0;
    __syncthreads();
    for (int k = t; k < ec; k += 256)
        atomicAdd(&deg[ebuf[eb + k] >> 16], 1);
    __syncthreads();
    int v = deg[t];
    sm[t] = v;
    __syncthreads();
    for (int o = 1; o < 256; o <<= 1) {
        int a = (t >= o) ? sm[t - o] : 0;
        __syncthreads();
        sm[t] += a;
        __syncthreads();
    }
    int node = b * 256 + t;
    if (node < NN) rowptr[node + 1] = eb + sm[t];
    if (node == 0) rowptr[0] = 0;
    cur[t] = sm[t] - v;   // exclusive
    __syncthreads();
    for (int k = t; k < ec; k += 256) {
        uint u = ebuf[eb + k];
        int nl = (int)(u >> 16);
        int r = atomicAdd(&cur[nl], 1);
        csrc[eb + r] = (int)(u & 0xFFFFu);
    }
}

// ---------------------------------------------------------------------------
// Weight conversion: W [128 x FOUT] fp32 -> bf16 hi/lo in MFMA-fragment order.
// ---------------------------------------------------------------------------
struct WPack {
    const float* W[8];
    ushort* Th[8];
    ushort* Tl[8];
    int fout[8];
};

__global__ __launch_bounds__(256) void k_conv_w(WPack p) {
    int wi = blockIdx.y;
    int fout = p.fout[wi];
    int total = 128 * fout;
    int i = blockIdx.x * 256 + threadIdx.x;
    if (i >= total) return;
    int k = i / fout;
    int n = i - k * fout;
    float f = p.W[wi][i];
    ushort h = f2bf(f);
    float lo = f - bf2f(h);
    int t = n >> 4, m = n & 15, c = k >> 5, quad = (k >> 3) & 3, j = k & 7;
    int flat = ((((t * 4 + c) * 4 + quad) * 16 + m) << 3) + j;
    p.Th[wi][flat] = h;
    p.Tl[wi][flat] = f2bf(lo);
}

// ---------------------------------------------------------------------------
// Fused split-bf16 MFMA GEMM + attention-dot epilogue.
// 512 threads = 8 waves x 16 rows = 128 rows per block; blockIdx.y = TS-wide
// t-slice. B tables for the slice are staged ONCE per block into LDS via
// global_load_lds (chunk = TS*4KB = 8KB = 512 thr x 16B, linear). After one
// barrier the inner loop is pure ds_read_b128 + MFMA: B waits are lgkmcnt,
// stores are vmcnt -> no interference; only the 8 A-loads touch vmcnt.
//   dotL[n,h] = 0.6 * att[h]·(xl[n]+bl)  -> DL[n*NH+h]
//   dotR[n,h] = 0.6 * att[h]·(xr[n]+br)  -> DR[n*NH+h]
// FOUT=128: one head per y-block, dot flushed directly. FOUT=64: atomicAdd
// partials into pre-zeroed DL/DR.
// ---------------------------------------------------------------------------
template <int FOUT, int NMAT, bool CVT, int TS>
__global__ __launch_bounds__(512) void k_gemm_fused(
    const float* __restrict__ Xf,
    const ushort* __restrict__ Xh, const ushort* __restrict__ Xl,
    const ushort* __restrict__ T0h, const ushort* __restrict__ T0l, const float* __restrict__ B0,
    const ushort* __restrict__ T1h, const ushort* __restrict__ T1l, const float* __restrict__ B1,
    const ushort* __restrict__ T2h, const ushort* __restrict__ T2l,
    const float* __restrict__ ATT, float* __restrict__ DL, float* __restrict__ DR,
    ushort* __restrict__ O0b, float* __restrict__ O1, float* __restrict__ O2)
{
    constexpr int CH = TS * 2048;                 // ushorts per staged chunk
    __shared__ __align__(16) ushort Bs[NMAT * 2 * CH];

    const int tid  = threadIdx.x;
    const int lane = tid & 63;
    const int wid  = tid >> 6;                    // 0..7
    const int m    = lane & 15;
    const int quad = lane >> 4;
    const int row0 = blockIdx.x * 128 + wid * 16;
    const int t0   = blockIdx.y * TS;

    // ---- stage B slice into LDS (one 8KB chunk per table) ----
    {
        const ushort* tbls[6] = {T0h, T0l, T1h, T1l, T2h, T2l};
        #pragma unroll
        for (int k = 0; k < 2 * NMAT; ++k) {
            gld_lds16(tbls[k] + (size_t)t0 * 2048 + (size_t)tid * 8,
                      &Bs[k * CH + tid * 8]);
        }
    }

    // ---- A fragments (per-wave rows) ----
    v8s ah[4], al[4];
    {
        int arow = row0 + m;
        if (arow > NN - 1) arow = NN - 1;
        #pragma unroll
        for (int c = 0; c < 4; ++c) {
            size_t off = (size_t)arow * 128 + c * 32 + quad * 8;
            if constexpr (CVT) {
                float4 f0 = *(const float4*)(Xf + off);
                float4 f1 = *(const float4*)(Xf + off + 4);
                const float fe[8] = {f0.x, f0.y, f0.z, f0.w, f1.x, f1.y, f1.z, f1.w};
                #pragma unroll
                for (int e = 0; e < 8; ++e) {
                    ushort h = f2bf(fe[e]);
                    float lo = fe[e] - bf2f(h);
                    ah[c][e] = (short)h;
                    al[c][e] = (short)(__float_as_uint(lo) >> 16);  // truncate lo
                }
            } else {
                ah[c] = *(const v8s*)(Xh + off);
                al[c] = *(const v8s*)(Xl + off);
            }
        }
    }

    __syncthreads();   // drains global_load_lds (vmcnt) + orders LDS

    float dp0[4] = {0.f, 0.f, 0.f, 0.f};
    float dp1[4] = {0.f, 0.f, 0.f, 0.f};

    #pragma unroll
    for (int tt = 0; tt < TS; ++tt) {
        const int t = t0 + tt;
        v4f a0 = {0.f, 0.f, 0.f, 0.f};
        v4f a1 = {0.f, 0.f, 0.f, 0.f};
        v4f a2 = {0.f, 0.f, 0.f, 0.f};
        #pragma unroll
        for (int c = 0; c < 4; ++c) {
            const int fo = tt * 2048 + (c * 4 + quad) * 128 + m * 8;
            v8s b0h = *(const v8s*)&Bs[0 * CH + fo];
            v8s b0l = *(const v8s*)&Bs[1 * CH + fo];
            v8s b1h = *(const v8s*)&Bs[2 * CH + fo];
            v8s b1l = *(const v8s*)&Bs[3 * CH + fo];
            a0 = __builtin_amdgcn_mfma_f32_16x16x32_bf16(al[c], b0h, a0, 0, 0, 0);
            a1 = __builtin_amdgcn_mfma_f32_16x16x32_bf16(al[c], b1h, a1, 0, 0, 0);
            a0 = __builtin_amdgcn_mfma_f32_16x16x32_bf16(ah[c], b0l, a0, 0, 0, 0);
            a1 = __builtin_amdgcn_mfma_f32_16x16x32_bf16(ah[c], b1l, a1, 0, 0, 0);
            a0 = __builtin_amdgcn_mfma_f32_16x16x32_bf16(ah[c], b0h, a0, 0, 0, 0);
            a1 = __builtin_amdgcn_mfma_f32_16x16x32_bf16(ah[c], b1h, a1, 0, 0, 0);
            if constexpr (NMAT == 3) {
                v8s b2h = *(const v8s*)&Bs[4 * CH + fo];
                v8s b2l = *(const v8s*)&Bs[5 * CH + fo];
                a2 = __builtin_amdgcn_mfma_f32_16x16x32_bf16(al[c], b2h, a2, 0, 0, 0);
                a2 = __builtin_amdgcn_mfma_f32_16x16x32_bf16(ah[c], b2l, a2, 0, 0, 0);
                a2 = __builtin_amdgcn_mfma_f32_16x16x32_bf16(ah[c], b2h, a2, 0, 0, 0);
            }
        }
        const int col = t * 16 + m;
        const float bad0 = B0[col];
        const float bad1 = B1[col];
        const float attc = ATT[col];
        #pragma unroll
        for (int j = 0; j < 4; ++j) {
            float o0v = a0[j] + bad0;
            float o1v = a1[j] + bad1;
            dp0[j] = fmaf(attc, o0v, dp0[j]);
            dp1[j] = fmaf(attc, o1v, dp1[j]);
            int r = row0 + quad * 4 + j;
            if (r < NN) {
                O0b[(size_t)r * FOUT + col] = f2bf(o0v);
                O1[(size_t)r * FOUT + col] = o1v;
                if constexpr (NMAT == 3) O2[(size_t)r * FOUT + col] = a2[j];
            }
        }
        if constexpr (FOUT == 128) {
            if ((t & 1) == 1) {   // head h = t>>1 complete -> reduce + store
                const int h = t >> 1;
                #pragma unroll
                for (int j = 0; j < 4; ++j) {
                    float s0 = sum16(dp0[j]);
                    float s1 = sum16(dp1[j]);
                    int r = row0 + quad * 4 + j;
                    if (m == 0 && r < NN) {
                        DL[(size_t)r * 4 + h] = 0.6f * s0;
                        DR[(size_t)r * 4 + h] = 0.6f * s1;
                    }
                    dp0[j] = 0.f;
                    dp1[j] = 0.f;
                }
            }
        }
    }
    if constexpr (FOUT == 64) {   // head spans all 4 t -> partial, atomic
        #pragma unroll
        for (int j = 0; j < 4; ++j) {
            float s0 = sum16(dp0[j]);
            float s1 = sum16(dp1[j]);
            int r = row0 + quad * 4 + j;
            if (m == 0 && r < NN) {
                atomicAdd(&DL[r], 0.6f * s0);
                atomicAdd(&DR[r], 0.6f * s1);
            }
        }
    }
}

// ---------------------------------------------------------------------------
// Aggregation layers 0/1: one wave per node, 8-edge main loop (4 gathers in
// flight) + masked 2-edge tail. logit decomposed:
//   logit = dotL[src,h] + dotR[dst,h] + sum_c (0.4*att_c)*|xl_c + xr_c|
// DL is a separate L2-hot table [NN*4].
// ---------------------------------------------------------------------------
__global__ __launch_bounds__(256) void k_agg01(const ushort* __restrict__ XLb,
                                               const float4* __restrict__ XR4,
                                               const float4* __restrict__ RES4,
                                               const float* __restrict__ att,
                                               const float* __restrict__ bias,
                                               const float* __restrict__ DL,
                                               const float* __restrict__ DR,
                                               const int* __restrict__ rowptr,
                                               const int* __restrict__ csrc,
                                               ushort* __restrict__ Hh,
                                               ushort* __restrict__ Hl) {
    const int lane = threadIdx.x & 63;
    const int wid = threadIdx.x >> 6;
    const int n = blockIdx.x * 4 + wid;
    if (n >= NN) return;
    const int beg = rowptr[n];
    const int end = rowptr[n + 1];
    const int half = lane >> 5;
    const uint j = lane & 31;
    const uint head = j >> 3;

    const float4 xr = XR4[(uint)n * 32u + j];
    float4 at = ((const float4*)att)[j];
    at.x *= 0.4f; at.y *= 0.4f; at.z *= 0.4f; at.w *= 0.4f;
    const float dRn = DR[(uint)n * 4u + head];
    float4 s = {0.f, 0.f, 0.f, 0.f};
    float d = 0.f;

#define EDGE01(U, DLV)  {                                             \
    float4 v = {bf2f((U).x), bf2f((U).y), bf2f((U).z), bf2f((U).w)};  \
    float t0 =      at.x * fabsf(v.x + xr.x);                         \
    t0 = fmaf(at.y, fabsf(v.y + xr.y), t0);                           \
    t0 = fmaf(at.z, fabsf(v.z + xr.z), t0);                           \
    t0 = fmaf(at.w, fabsf(v.w + xr.w), t0);                           \
    float p = expclamp(sum8(t0) + (DLV) + dRn);                       \
    d += p;                                                            \
    s.x = fmaf(p, v.x, s.x); s.y = fmaf(p, v.y, s.y);                 \
    s.z = fmaf(p, v.z, s.z); s.w = fmaf(p, v.w, s.w); }

    int i = beg;
    for (; i + 8 <= end; i += 8) {
        uint sa = (uint)csrc[i + half];
        uint sb = (uint)csrc[i + 2 + half];
        uint sc = (uint)csrc[i + 4 + half];
        uint sd = (uint)csrc[i + 6 + half];
        ushort4 ua = *(const ushort4*)(XLb + (size_t)sa * 128u + 4u * j);
        float  da_ = DL[(size_t)sa * 4u + head];
        ushort4 ub = *(const ushort4*)(XLb + (size_t)sb * 128u + 4u * j);
        float  db_ = DL[(size_t)sb * 4u + head];
        ushort4 uc = *(const ushort4*)(XLb + (size_t)sc * 128u + 4u * j);
        float  dc_ = DL[(size_t)sc * 4u + head];
        ushort4 ud = *(const ushort4*)(XLb + (size_t)sd * 128u + 4u * j);
        float  dd_ = DL[(size_t)sd * 4u + head];
        EDGE01(ua, da_)
        EDGE01(ub, db_)
        EDGE01(uc, dc_)
        EDGE01(ud, dd_)
    }
    for (; i < end; i += 2) {
        int ia = i + half;
        if (ia > end - 1) ia = end - 1;
        uint sa = (uint)csrc[ia];
        ushort4 ua = *(const ushort4*)(XLb + (size_t)sa * 128u + 4u * j);
        float  da_ = DL[(size_t)sa * 4u + head];
        float4 v = {bf2f(ua.x), bf2f(ua.y), bf2f(ua.z), bf2f(ua.w)};
        float t0 =      at.x * fabsf(v.x + xr.x);
        t0 = fmaf(at.y, fabsf(v.y + xr.y), t0);
        t0 = fmaf(at.z, fabsf(v.z + xr.z), t0);
        t0 = fmaf(at.w, fabsf(v.w + xr.w), t0);
        float p = expclamp(sum8(t0) + da_ + dRn);
        if (half && (i + 1 >= end)) p = 0.f;
        d += p;
        s.x = fmaf(p, v.x, s.x); s.y = fmaf(p, v.y, s.y);
        s.z = fmaf(p, v.z, s.z); s.w = fmaf(p, v.w, s.w);
    }
#undef EDGE01

    d   += __shfl_xor(d, 32);
    s.x += __shfl_xor(s.x, 32);
    s.y += __shfl_xor(s.y, 32);
    s.z += __shfl_xor(s.z, 32);
    s.w += __shfl_xor(s.w, 32);

    if (half == 0) {
        float inv = (d > 0.f) ? 1.f / d : 0.f;
        float4 rv = RES4[(uint)n * 32u + j];
        float4 bv = ((const float4*)bias)[j];
        float o0 = fmaf(s.x, inv, rv.x + bv.x);
        float o1 = fmaf(s.y, inv, rv.y + bv.y);
        float o2 = fmaf(s.z, inv, rv.z + bv.z);
        float o3 = fmaf(s.w, inv, rv.w + bv.w);
        o0 = o0 > 0.f ? o0 : __expf(o0) - 1.f;   // ELU
        o1 = o1 > 0.f ? o1 : __expf(o1) - 1.f;
        o2 = o2 > 0.f ? o2 : __expf(o2) - 1.f;
        o3 = o3 > 0.f ? o3 : __expf(o3) - 1.f;
        ushort4 h, l;
        h.x = f2bf(o0); l.x = f2bf(o0 - bf2f(h.x));
        h.y = f2bf(o1); l.y = f2bf(o1 - bf2f(h.y));
        h.z = f2bf(o2); l.z = f2bf(o2 - bf2f(h.z));
        h.w = f2bf(o3); l.w = f2bf(o3 - bf2f(h.w));
        *(ushort4*)(Hh + (uint)n * 128u + 4u * j) = h;
        *(ushort4*)(Hl + (uint)n * 128u + 4u * j) = l;
    }
}

// ---------------------------------------------------------------------------
// Aggregation layer 2: F=64, H=1. 8 edges per iteration (2 masked
// quad-passes). sum16 over channel lanes. DL/DR are [NN] fp32.
// ---------------------------------------------------------------------------
__global__ __launch_bounds__(256) void k_agg2(const ushort* __restrict__ XLb,
                                              const float4* __restrict__ XR4,
                                              const float* __restrict__ att,
                                              const float* __restrict__ bias,
                                              const float* __restrict__ DL,
                                              const float* __restrict__ DR,
                                              const int* __restrict__ rowptr,
                                              const int* __restrict__ csrc,
                                              float* __restrict__ OUT) {
    const int lane = threadIdx.x & 63;
    const int wid = threadIdx.x >> 6;
    const int n = blockIdx.x * 4 + wid;
    if (n >= NN) return;
    const int beg = rowptr[n];
    const int end = rowptr[n + 1];
    const int q = lane >> 4;
    const uint jj = lane & 15;

    const float4 xr = XR4[(uint)n * 16u + jj];
    float4 at = ((const float4*)att)[jj];
    at.x *= 0.4f; at.y *= 0.4f; at.z *= 0.4f; at.w *= 0.4f;
    const float dRn = DR[n];
    float4 s = {0.f, 0.f, 0.f, 0.f};
    float d = 0.f;
    const int e1 = end - 1;

    for (int i = beg; i < end; i += 8) {
        int i0 = i + q;
        int i1 = i + 4 + q;
        uint s0 = (uint)csrc[min(i0, e1)];
        uint s1 = (uint)csrc[min(i1, e1)];
        ushort4 u0 = *(const ushort4*)(XLb + (size_t)s0 * 64u + 4u * jj);
        float  dl0 = DL[s0];
        ushort4 u1 = *(const ushort4*)(XLb + (size_t)s1 * 64u + 4u * jj);
        float  dl1 = DL[s1];
        #pragma unroll
        for (int u = 0; u < 2; ++u) {
            ushort4 uv = (u == 0) ? u0 : u1;
            float  dlv = (u == 0) ? dl0 : dl1;
            int ii = (u == 0) ? i0 : i1;
            float4 v = {bf2f(uv.x), bf2f(uv.y), bf2f(uv.z), bf2f(uv.w)};
            float t0 =      at.x * fabsf(v.x + xr.x);
            t0 = fmaf(at.y, fabsf(v.y + xr.y), t0);
            t0 = fmaf(at.z, fabsf(v.z + xr.z), t0);
            t0 = fmaf(at.w, fabsf(v.w + xr.w), t0);
            float p = expclamp(sum16(t0) + dlv + dRn);
            if (ii >= end) p = 0.f;
            d += p;
            s.x = fmaf(p, v.x, s.x); s.y = fmaf(p, v.y, s.y);
            s.z = fmaf(p, v.z, s.z); s.w = fmaf(p, v.w, s.w);
        }
    }

    d   += __shfl_xor(d, 16);   d   += __shfl_xor(d, 32);
    s.x += __shfl_xor(s.x, 16); s.x += __shfl_xor(s.x, 32);
    s.y += __shfl_xor(s.y, 16); s.y += __shfl_xor(s.y, 32);
    s.z += __shfl_xor(s.z, 16); s.z += __shfl_xor(s.z, 32);
    s.w += __shfl_xor(s.w, 16); s.w += __shfl_xor(s.w, 32);

    if (lane < 16) {
        float inv = (d > 0.f) ? 1.f / d : 0.f;
        float4 bv = ((const float4*)bias)[jj];
        float4 o;
        o.x = fmaf(s.x, inv, bv.x);
        o.y = fmaf(s.y, inv, bv.y);
        o.z = fmaf(s.z, inv, bv.z);
        o.w = fmaf(s.w, inv, bv.w);
        *(float4*)(OUT + (uint)n * 64u + 4u * jj) = o;
    }
}

// ---------------------------------------------------------------------------
extern "C" void kernel_launch(void* const* d_in, const int* in_sizes, int n_in,
                              void* d_out, int out_size, void* d_ws, size_t ws_size,
                              hipStream_t stream) {
    const float* x    = (const float*)d_in[0];
    const int*   ei   = (const int*)d_in[1];
    const int*   esrc = ei;
    const int*   edst = ei + EE;

    const float* Wl0 = (const float*)d_in[2];
    const float* bl0 = (const float*)d_in[3];
    const float* Wr0 = (const float*)d_in[4];
    const float* br0 = (const float*)d_in[5];
    const float* at0 = (const float*)d_in[6];
    const float* b0  = (const float*)d_in[7];
    const float* rs0 = (const float*)d_in[8];
    const float* Wl1 = (const float*)d_in[9];
    const float* bl1 = (const float*)d_in[10];
    const float* Wr1 = (const float*)d_in[11];
    const float* br1 = (const float*)d_in[12];
    const float* at1 = (const float*)d_in[13];
    const float* b1  = (const float*)d_in[14];
    const float* rs1 = (const float*)d_in[15];
    const float* Wl2 = (const float*)d_in[16];
    const float* bl2 = (const float*)d_in[17];
    const float* Wr2 = (const float*)d_in[18];
    const float* br2 = (const float*)d_in[19];
    const float* at2 = (const float*)d_in[20];
    const float* b2  = (const float*)d_in[21];

    float* out = (float*)d_out;

    // --- workspace layout ---
    ushort* XLb = (ushort*)d_ws;               // [NN*128] bf16 (gather payload)
    float* XR  = (float*)(XLb + (size_t)NN * 128);    // [NN*128] fp32
    float* RES = XR + (size_t)NN * 128;               // [NN*128] fp32
    ushort* Xh = (ushort*)(RES + (size_t)NN * 128);   // [NN*128] bf16-hi (H)
    ushort* Xl_ = Xh + (size_t)NN * 128;              // [NN*128] bf16-lo (H)
    float* DLarr = (float*)(Xl_ + (size_t)NN * 128);  // [NN*4] fp32 dotL
    float* DRarr = DLarr + (size_t)NN * 4;            // [NN*4] fp32 dotR
    ushort* Wth = (ushort*)(DRarr + (size_t)NN * 4);
    const int wsz[8] = {16384, 16384, 16384, 16384, 16384, 16384, 8192, 8192};
    ushort* th[8]; ushort* tl[8];
    {
        ushort* p = Wth;
        for (int i = 0; i < 8; ++i) { th[i] = p; p += wsz[i]; }
        for (int i = 0; i < 8; ++i) { tl[i] = p; p += wsz[i]; }
    }
    int* bcnt   = (int*)(Wth + 2 * (6 * 16384 + 2 * 8192));  // 256 (memset)
    int* bbase  = bcnt + 256;                  // 256
    int* bcur   = bbase + 256;                 // 256
    int* rowptr = bcur + 256;                  // NN+1
    int* csrc   = rowptr + (NN + 1);           // EE
    uint* ebuf  = (uint*)(csrc + EE);          // EE

    // --- bucketed CSR build (graph identical across layers) ---
    hipMemsetAsync(bcnt, 0, 256 * sizeof(int), stream);
    const int ebk = (EE + EPB - 1) / EPB;      // 196
    k_bktcnt<<<ebk, 256, 0, stream>>>(edst, bcnt);
    k_bscan<<<1, 256, 0, stream>>>(bcnt, bbase, bcur);
    k_bktplace<<<ebk, 256, 0, stream>>>(esrc, edst, bcur, ebuf);
    k_bktfin<<<NBK, 256, 0, stream>>>(ebuf, bbase, bcnt, rowptr, csrc);

    // --- weight conversion ---
    WPack wp;
    const float* Ws[8] = {Wl0, Wr0, rs0, Wl1, Wr1, rs1, Wl2, Wr2};
    const int fouts[8] = {128, 128, 128, 128, 128, 128, 64, 64};
    for (int i = 0; i < 8; ++i) { wp.W[i] = Ws[i]; wp.Th[i] = th[i]; wp.Tl[i] = tl[i]; wp.fout[i] = fouts[i]; }
    k_conv_w<<<dim3(64, 8), 256, 0, stream>>>(wp);

    const int gemm_gx = (NN + 127) / 128;      // 391 row-tiles (128 rows/block)
    const int agg_grid = (NN + 3) / 4;

    // --- Layer 0 (A from fp32 x; 3 weight mats fused; grid.y = t-slice) ---
    k_gemm_fused<128, 3, true, 2><<<dim3(gemm_gx, 4), 512, 0, stream>>>(x, nullptr, nullptr,
        th[0], tl[0], bl0, th[1], tl[1], br0, th[2], tl[2], at0, DLarr, DRarr, XLb, XR, RES);
    k_agg01<<<agg_grid, 256, 0, stream>>>(XLb, (const float4*)XR, (const float4*)RES,
        at0, b0, DLarr, DRarr, rowptr, csrc, Xh, Xl_);

    // --- Layer 1 ---
    k_gemm_fused<128, 3, false, 2><<<dim3(gemm_gx, 4), 512, 0, stream>>>(nullptr, Xh, Xl_,
        th[3], tl[3], bl1, th[4], tl[4], br1, th[5], tl[5], at1, DLarr, DRarr, XLb, XR, RES);
    k_agg01<<<agg_grid, 256, 0, stream>>>(XLb, (const float4*)XR, (const float4*)RES,
        at1, b1, DLarr, DRarr, rowptr, csrc, Xh, Xl_);

    // --- Layer 2 (heads=1, C=64; dot partials via atomics into zeroed DL/DR) ---
    hipMemsetAsync(DLarr, 0, NN * sizeof(float), stream);
    hipMemsetAsync(DRarr, 0, NN * sizeof(float), stream);
    k_gemm_fused<64, 2, false, 2><<<dim3(gemm_gx, 2), 512, 0, stream>>>(nullptr, Xh, Xl_,
        th[6], tl[6], bl2, th[7], tl[7], br2, nullptr, nullptr, at2, DLarr, DRarr, XLb, XR, nullptr);
    k_agg2<<<agg_grid, 256, 0, stream>>>(XLb, (const float4*)XR, at2, b2, DLarr, DRarr, rowptr, csrc, out);
}